// Round 9
// baseline (105.030 us; speedup 1.0000x reference)
//
#include <hip/hip_runtime.h>
#include <math.h>

#define EPS      0.1f
#define INV_EPS  10.0f
#define THRESH   0.1f
#define MAX_IT   20

// Problem sizes (fixed by reference setup_inputs)
#define BB 4
#define NN 1024
#define MM 1024
#define DD 512

#define MU_P (1.0f / 1024.0f + 1e-8f)

// Sinkhorn loop config: 128 blocks x 512 threads, 32 rows/block, 4 rows/wave
// (proven best, R0/R1/R8). Regular launch (R8: coop launch cost ~25 us).
#define GBLK 128
#define TBLK 512

// workspace layout (float offsets) — xb/yb/nx/ny/nup all eliminated
#define OFF_K    ((size_t)0)               // K = exp(-C/eps) [B,N,M] bf16 (8.4 MB)
#define OFF_CS   ((size_t)2097152)         // colsum rotation [3][4096]
#define OFF_FLG  (OFF_CS + 12288)          // barrier flags [2][128] ulong

#define GLDA 40  // padded ushort row stride (80 B): bank-balanced, 16B-aligned rows

typedef __bf16 bf16x8 __attribute__((ext_vector_type(8)));
typedef float f32x4 __attribute__((ext_vector_type(4)));
typedef unsigned long long u64;

__device__ __forceinline__ float wave_reduce_sum(float x) {
#pragma unroll
  for (int off = 32; off > 0; off >>= 1) x += __shfl_xor(x, off, 64);
  return x;
}

// pack two floats to bf16x2 (RNE via compiler cast)
__device__ __forceinline__ uint pk2(float a, float b) {
  __bf16 ha = (__bf16)a, hb = (__bf16)b;
  return (uint)*(ushort*)&ha | ((uint)*(ushort*)&hb << 16);
}

__device__ __forceinline__ void unpack8(uint4 k, float* kf) {
  kf[0] = __uint_as_float(k.x << 16);
  kf[1] = __uint_as_float(k.x & 0xffff0000u);
  kf[2] = __uint_as_float(k.y << 16);
  kf[3] = __uint_as_float(k.y & 0xffff0000u);
  kf[4] = __uint_as_float(k.z << 16);
  kf[5] = __uint_as_float(k.z & 0xffff0000u);
  kf[6] = __uint_as_float(k.w << 16);
  kf[7] = __uint_as_float(k.w & 0xffff0000u);
}

// -------- MFMA bf16 GEMM with FUSED prep: reads fp32 x/y, converts to bf16
// in-register while staging, accumulates row sums-of-squares on the fly
// (norms from ORIGINAL fp32, reference semantics). Also does sinkhorn state
// init (colsum buf1, flags, out) — kernel boundary releases it for sinkhorn.
// 128x64 tile, 256 thr, grid (16,8,4) = 512 blocks -> 2 blocks/CU. --------
__global__ void __launch_bounds__(256) gemm_kernel(const float* __restrict__ x,
                                                   const float* __restrict__ y,
                                                   ushort* __restrict__ K,
                                                   float* __restrict__ colsum,
                                                   int* __restrict__ flagsi,
                                                   float* __restrict__ out) {
  __shared__ ushort Ah[128 * GLDA];    // 10.2 KB
  __shared__ ushort Bh[64 * GLDA];     // 5.1 KB
  __shared__ float s_nx[128], s_ny[64];

  const int b = blockIdx.z;
  const int i0 = blockIdx.y * 128;   // m-tile (8)
  const int j0 = blockIdx.x * 64;    // n-tile (16)
  const int t = threadIdx.x;
  const int w = t >> 6, lane = t & 63;
  const int m16 = lane & 15, q = lane >> 4;
  const int wm = (w & 1) * 64, wn = (w >> 1) * 32;

  // ---- sinkhorn state init (spread across the 512 blocks) ----
  {
    const int bid = blockIdx.x + (blockIdx.y << 4) + (blockIdx.z << 7);
    const int gt = bid * 256 + t;
    if (gt < BB * MM) colsum[4096 + gt] = 0.f;   // buf1 = iteration 0 target
    if (gt < 512) flagsi[gt] = 0;                // 2 x 128 ulong flag slots
    if (gt < BB) out[gt] = 0.f;
  }

  // staging: A 128 rows x 32 elems (2 thr/row, 16 elems each = 4 float4),
  //          B  64 rows x 32 elems (4 thr/row,  8 elems each = 2 float4)
  const int srA = t >> 1, soA = (t & 1) * 16;
  const int srB = t >> 2, soB = (t & 3) * 8;

  const float* xrow = x + ((size_t)b * NN + i0 + srA) * DD + soA;
  const float* yrow = y + ((size_t)b * MM + j0 + srB) * DD + soB;

  f32x4 acc[4][2];
#pragma unroll
  for (int mi = 0; mi < 4; ++mi)
#pragma unroll
    for (int ni = 0; ni < 2; ++ni) acc[mi][ni] = (f32x4)0.f;

  float ssA = 0.f, ssB = 0.f;
  for (int k0 = 0; k0 < DD; k0 += 32) {
    float4 a0 = *(const float4*)(xrow + k0);
    float4 a1 = *(const float4*)(xrow + k0 + 4);
    float4 a2 = *(const float4*)(xrow + k0 + 8);
    float4 a3 = *(const float4*)(xrow + k0 + 12);
    float4 b0 = *(const float4*)(yrow + k0);
    float4 b1 = *(const float4*)(yrow + k0 + 4);
    ssA += a0.x * a0.x + a0.y * a0.y + a0.z * a0.z + a0.w * a0.w +
           a1.x * a1.x + a1.y * a1.y + a1.z * a1.z + a1.w * a1.w +
           a2.x * a2.x + a2.y * a2.y + a2.z * a2.z + a2.w * a2.w +
           a3.x * a3.x + a3.y * a3.y + a3.z * a3.z + a3.w * a3.w;
    ssB += b0.x * b0.x + b0.y * b0.y + b0.z * b0.z + b0.w * b0.w +
           b1.x * b1.x + b1.y * b1.y + b1.z * b1.z + b1.w * b1.w;
    uint4 pa0 = make_uint4(pk2(a0.x, a0.y), pk2(a0.z, a0.w), pk2(a1.x, a1.y), pk2(a1.z, a1.w));
    uint4 pa1 = make_uint4(pk2(a2.x, a2.y), pk2(a2.z, a2.w), pk2(a3.x, a3.y), pk2(a3.z, a3.w));
    uint4 pb0 = make_uint4(pk2(b0.x, b0.y), pk2(b0.z, b0.w), pk2(b1.x, b1.y), pk2(b1.z, b1.w));
    __syncthreads();
    *(uint4*)&Ah[srA * GLDA + soA] = pa0;
    *(uint4*)&Ah[srA * GLDA + soA + 8] = pa1;
    *(uint4*)&Bh[srB * GLDA + soB] = pb0;
    __syncthreads();

    bf16x8 ahf[4], bhf[2];
#pragma unroll
    for (int mi = 0; mi < 4; ++mi)
      ahf[mi] = *(const bf16x8*)&Ah[(wm + mi * 16 + m16) * GLDA + q * 8];
#pragma unroll
    for (int ni = 0; ni < 2; ++ni)
      bhf[ni] = *(const bf16x8*)&Bh[(wn + ni * 16 + m16) * GLDA + q * 8];
#pragma unroll
    for (int mi = 0; mi < 4; ++mi)
#pragma unroll
      for (int ni = 0; ni < 2; ++ni)
        acc[mi][ni] = __builtin_amdgcn_mfma_f32_16x16x32_bf16(ahf[mi], bhf[ni], acc[mi][ni], 0, 0, 0);
  }

  // ---- row norms from the fp32 partial sums (pair/quad shfl combine) ----
  ssA += __shfl_xor(ssA, 1, 64);               // partner thread, same A row
  ssB += __shfl_xor(ssB, 1, 64);               // 4 threads share a B row
  ssB += __shfl_xor(ssB, 2, 64);
  if ((t & 1) == 0) s_nx[srA] = sqrtf(ssA);
  if ((t & 3) == 0) s_ny[srB] = sqrtf(ssB);
  __syncthreads();

  // epilogue: K = exp(-(1 - dot/den)/eps), bf16
#pragma unroll
  for (int mi = 0; mi < 4; ++mi)
#pragma unroll
    for (int ni = 0; ni < 2; ++ni)
#pragma unroll
      for (int r = 0; r < 4; ++r) {
        const int m = wm + mi * 16 + q * 4 + r;
        const int n = wn + ni * 16 + m16;
        float den = fmaxf(s_nx[m] * s_ny[n], 1e-8f);
        float cv = 1.0f - acc[mi][ni][r] / den;
        float kf = __expf(-cv * INV_EPS);
        __bf16 hb = (__bf16)kf;
        K[((size_t)b * NN + i0 + m) * MM + j0 + n] = *(ushort*)&hb;
      }
}

// -------- persistent Sinkhorn, ONE barrier per iteration (round-1 verbatim;
// only change: reads nu directly with +1e-8 inline, nup buffer eliminated) --------
__global__ void __launch_bounds__(TBLK, 2) sinkhorn_kernel(
    const ushort* __restrict__ K, float* __restrict__ colsum,
    const float* __restrict__ nu, u64* __restrict__ flags,
    float* __restrict__ out) {
  const int tid = threadIdx.x;
  const int bid = blockIdx.x;
  const int lane = tid & 63;
  const int w = tid >> 6;                 // 0..7
  const int b = bid >> 5;                 // batch (32 blocks per batch)
  const int rbase = (bid & 31) * 32;      // first owned row within batch

  __shared__ float swv[1024];
  __shared__ float spart[8][1024];        // 32 KB per-wave column partials
  __shared__ float s_red;
  __shared__ int s_conv;

  const float eps_log_mu = EPS * __logf(MU_P);
  float u_prev[4] = {0.f, 0.f, 0.f, 0.f};
  float wu_reg[4] = {0.f, 0.f, 0.f, 0.f};
  int T = 0;

  // ---- hoist this wave's 4 K-rows into registers, unpacked fp32 ----
  float kf[4][16];
#pragma unroll
  for (int rr = 0; rr < 4; ++rr) {
    const uint4* kp = (const uint4*)(K + ((size_t)b * NN + rbase + w * 4 + rr) * MM);
    uint4 k0 = kp[lane];
    uint4 k1 = kp[lane + 64];
    unpack8(k0, kf[rr]);
    unpack8(k1, kf[rr] + 8);
  }

  for (int it = 0; it < MAX_IT; ++it) {
    const int genv = it + 1;
    // ---- stage wv (local v reconstruction; it=0: v=0 -> wv=1) ----
    if (tid == 0) s_red = 0.f;
    if (it == 0) {
      swv[tid] = 1.f;
      swv[tid + 512] = 1.f;
    } else {
      const float* cs = colsum + (it % 3) * 4096 + b * MM;
      float c0 = __hip_atomic_load(cs + tid, __ATOMIC_RELAXED, __HIP_MEMORY_SCOPE_AGENT);
      float c1 = __hip_atomic_load(cs + tid + 512, __ATOMIC_RELAXED, __HIP_MEMORY_SCOPE_AGENT);
      swv[tid] = (nu[b * MM + tid] + 1e-8f) / c0;
      swv[tid + 512] = (nu[b * MM + tid + 512] + 1e-8f) / c1;
    }
    __syncthreads();

    float wvr[16];
    {
      const float4* wp = (const float4*)swv;
      *(float4*)&wvr[0] = wp[lane * 2];
      *(float4*)&wvr[4] = wp[lane * 2 + 1];
      *(float4*)&wvr[8] = wp[128 + lane * 2];
      *(float4*)&wvr[12] = wp[129 + lane * 2];
    }
    float creg[16];
#pragma unroll
    for (int t2 = 0; t2 < 16; ++t2) creg[t2] = 0.f;

    float werr = 0.f;
#pragma unroll
    for (int rr = 0; rr < 4; ++rr) {
      float s = 0.f;
#pragma unroll
      for (int t2 = 0; t2 < 16; ++t2) s = fmaf(kf[rr][t2], wvr[t2], s);
      s = wave_reduce_sum(s);
      float unv = eps_log_mu - EPS * __logf(s);
      werr += fabsf(unv - u_prev[rr]);
      u_prev[rr] = unv;
      float wu = MU_P / s;          // exp(u_new/eps), exactly
      wu_reg[rr] = wu;
#pragma unroll
      for (int t2 = 0; t2 < 16; ++t2) creg[t2] = fmaf(wu, kf[rr][t2], creg[t2]);
    }
    if (lane == 0) atomicAdd(&s_red, werr);

    // publish per-wave column partials to LDS
    {
      float* pr = &spart[w][0];
      *(float4*)&pr[lane * 8] = *(float4*)&creg[0];
      *(float4*)&pr[lane * 8 + 4] = *(float4*)&creg[4];
      *(float4*)&pr[512 + lane * 8] = *(float4*)&creg[8];
      *(float4*)&pr[512 + lane * 8 + 4] = *(float4*)&creg[12];
    }
    __syncthreads();

    // cross-wave reduce + atomic add into next colsum; zero rotation buffer
    {
      float* csn = colsum + ((it + 1) % 3) * 4096 + b * MM;
      const int j0 = tid * 2;
      float s0 = 0.f, s1 = 0.f;
#pragma unroll
      for (int ww = 0; ww < 8; ++ww) {
        float2 p = *(const float2*)&spart[ww][j0];
        s0 += p.x;
        s1 += p.y;
      }
      unsafeAtomicAdd(&csn[j0], s0);
      unsafeAtomicAdd(&csn[j0 + 1], s1);
      if (tid < 32) {
        float* csz = colsum + ((it + 2) % 3) * 4096;
        __hip_atomic_store(&csz[bid * 32 + tid], 0.f, __ATOMIC_RELAXED, __HIP_MEMORY_SCOPE_AGENT);
      }
    }

    // ---- all-to-all barrier: publish {gen, err}, poll, local conv decision ----
    asm volatile("s_waitcnt vmcnt(0)" ::: "memory");
    __syncthreads();
    if (tid == 0) {
      u64 f = ((u64)(uint)genv << 32) | (u64)__float_as_uint(s_red);
      __hip_atomic_store(&flags[(genv & 1) * GBLK + bid], f, __ATOMIC_RELAXED, __HIP_MEMORY_SCOPE_AGENT);
    }
    if (tid < 64) {
      const u64* fl = flags + (genv & 1) * GBLK;
      u64 f0, f1;
      for (;;) {
        f0 = __hip_atomic_load(fl + tid, __ATOMIC_RELAXED, __HIP_MEMORY_SCOPE_AGENT);
        f1 = __hip_atomic_load(fl + tid + 64, __ATOMIC_RELAXED, __HIP_MEMORY_SCOPE_AGENT);
        if (__all(((f0 >> 32) >= (u64)genv) && ((f1 >> 32) >= (u64)genv))) break;
        __builtin_amdgcn_s_sleep(1);
      }
      float e = __uint_as_float((uint)f0) + __uint_as_float((uint)f1);
      e = wave_reduce_sum(e);
      if (tid == 0) s_conv = (e * (1.0f / (float)BB) < THRESH) ? 1 : 0;
    }
    __syncthreads();
    T = it;
    if (s_conv) break;
  }

  // ---- final: reconstruct converged wv locally, accumulate transport cost ----
  {
    const float* cs = colsum + ((T + 1) % 3) * 4096 + b * MM;
    float c0 = __hip_atomic_load(cs + tid, __ATOMIC_RELAXED, __HIP_MEMORY_SCOPE_AGENT);
    float c1 = __hip_atomic_load(cs + tid + 512, __ATOMIC_RELAXED, __HIP_MEMORY_SCOPE_AGENT);
    swv[tid] = (nu[b * MM + tid] + 1e-8f) / c0;
    swv[tid + 512] = (nu[b * MM + tid + 512] + 1e-8f) / c1;
  }
  if (tid == 0) s_red = 0.f;
  __syncthreads();

  float wvr[16];
  {
    const float4* wp = (const float4*)swv;
    *(float4*)&wvr[0] = wp[lane * 2];
    *(float4*)&wvr[4] = wp[lane * 2 + 1];
    *(float4*)&wvr[8] = wp[128 + lane * 2];
    *(float4*)&wvr[12] = wp[129 + lane * 2];
  }

  float wcost = 0.f;
#pragma unroll
  for (int rr = 0; rr < 4; ++rr) {
    float s = 0.f;
#pragma unroll
    for (int t2 = 0; t2 < 16; ++t2)
      s = fmaf(kf[rr][t2] * wvr[t2], -EPS * __logf(kf[rr][t2]), s);   // pi * C, C = -eps log K
    s = wave_reduce_sum(s) * wu_reg[rr];
    if (lane == 0) wcost += s;
  }
  if (lane == 0) atomicAdd(&s_red, wcost);
  __syncthreads();
  if (tid == 0) atomicAdd(out + b, s_red);
}

extern "C" void kernel_launch(void* const* d_in, const int* in_sizes, int n_in,
                              void* d_out, int out_size, void* d_ws, size_t ws_size,
                              hipStream_t stream) {
  const float* x = (const float*)d_in[0];
  const float* y = (const float*)d_in[1];
  const float* nu = (const float*)d_in[2];
  float* out = (float*)d_out;
  float* ws = (float*)d_ws;

  ushort* K = (ushort*)(ws + OFF_K);
  float* cs = ws + OFF_CS;
  u64* flg = (u64*)(ws + OFF_FLG);

  gemm_kernel<<<dim3(16, 8, 4), 256, 0, stream>>>(x, y, K, cs, (int*)flg, out);

  sinkhorn_kernel<<<GBLK, TBLK, 0, stream>>>(K, cs, nu, flg, out);
}

// Round 10
// 101.834 us; speedup vs baseline: 1.0314x; 1.0314x over previous
//
#include <hip/hip_runtime.h>
#include <math.h>

#define EPS      0.1f
#define INV_EPS  10.0f
#define THRESH   0.1f
#define MAX_IT   20

// Problem sizes (fixed by reference setup_inputs)
#define BB 4
#define NN 1024
#define MM 1024
#define DD 512

#define MU_P (1.0f / 1024.0f + 1e-8f)

// Sinkhorn loop config: 128 blocks x 512 threads, 32 rows/block, 4 rows/wave
// (proven best: R0/R1/R8; 64 and 256 participants both measured worse).
// Regular launch (R8: cooperative-launch machinery cost ~25 us).
#define GBLK 128
#define TBLK 512

// workspace layout (float offsets)
#define OFF_K    ((size_t)0)                   // K = exp(-C/eps) [B,N,M] bf16 (8.4 MB)
#define OFF_XB   ((size_t)2097152)             // x in bf16 [B,N,D] (4.2 MB)
#define OFF_YB   ((size_t)3145728)             // y in bf16 [B,M,D] (4.2 MB)
#define OFF_NX   ((size_t)4194304)             // |x_i| [B*N]
#define OFF_NY   (OFF_NX + 4096)               // |y_j| [B*M]
#define OFF_NUP  (OFF_NY + 4096)               // nu + 1e-8 [B*M]
#define OFF_CS   (OFF_NUP + 4096)              // colsum rotation [3][4096]
#define OFF_FLG  (OFF_CS + 12288)              // barrier flags [2][128] ulong

#define GLDA 40  // padded ushort row stride (80 B): bank-balanced, 16B-aligned rows

typedef __bf16 bf16x8 __attribute__((ext_vector_type(8)));
typedef float f32x4 __attribute__((ext_vector_type(4)));
typedef unsigned long long u64;

__device__ __forceinline__ float wave_reduce_sum(float x) {
#pragma unroll
  for (int off = 32; off > 0; off >>= 1) x += __shfl_xor(x, off, 64);
  return x;
}

// pack two floats to bf16x2 (RNE via compiler cast)
__device__ __forceinline__ uint pk2(float a, float b) {
  __bf16 ha = (__bf16)a, hb = (__bf16)b;
  return (uint)*(ushort*)&ha | ((uint)*(ushort*)&hb << 16);
}

// -------- prep: fp32 norms of x/y rows (from ORIGINAL fp32), x/y -> bf16,
// sinkhorn state init (merged). One wave per 512-float row. --------
__global__ void __launch_bounds__(256) prep_kernel(const float* __restrict__ x,
                                                   const float* __restrict__ y,
                                                   ushort* __restrict__ xb,
                                                   ushort* __restrict__ yb,
                                                   float* __restrict__ nx,
                                                   float* __restrict__ ny,
                                                   const float* __restrict__ nu,
                                                   float* nup, float* colsum,
                                                   int* flagsi, float* out) {
  const int tid = threadIdx.x;
  int gt = blockIdx.x * 256 + tid;
  if (gt < BB * MM) {
    nup[gt] = nu[gt] + 1e-8f;
    colsum[4096 + gt] = 0.f;      // colsum[1] is iteration 0's add target
  }
  if (gt < 512) flagsi[gt] = 0;   // 2 x 128 ulong flag slots
  if (gt < BB) out[gt] = 0.f;

  const int w = tid >> 6, lane = tid & 63;
  const int r = blockIdx.x * 4 + w;                 // 0..8191
  const bool isx = (r < BB * NN);
  const float* src = isx ? (x + (size_t)r * DD)
                         : (y + (size_t)(r - BB * NN) * DD);
  ushort* dst = isx ? (xb + (size_t)r * DD)
                    : (yb + (size_t)(r - BB * NN) * DD);
  const float4* s4 = (const float4*)src;
  float4 a = s4[lane * 2];          // 8 contiguous floats per lane
  float4 b = s4[lane * 2 + 1];
  float ss = a.x * a.x + a.y * a.y + a.z * a.z + a.w * a.w +
             b.x * b.x + b.y * b.y + b.z * b.z + b.w * b.w;
  uint4 pk = make_uint4(pk2(a.x, a.y), pk2(a.z, a.w), pk2(b.x, b.y), pk2(b.z, b.w));
  *(uint4*)(dst + lane * 8) = pk;
  ss = wave_reduce_sum(ss);
  if (lane == 0) {
    float n = sqrtf(ss);
    if (isx) nx[r] = n; else ny[r - BB * NN] = n;
  }
}

// -------- MFMA bf16 GEMM (bf16-staged): dot = X Y^T, 64x64 tile, 256 thr,
// grid (16,16,4) = 1024 blocks -> 4 blocks/CU (16 waves/CU) so one block's
// staging latency hides under the others' MFMA (2/CU still exposed latency).
// 4 waves of 2x2 16x16x32 frags; per k-step each thread stages exactly one
// uint4 of A and one of B. Epilogue K = exp(-(1-dot/den)/eps), bf16. --------
__global__ void __launch_bounds__(256) gemm_kernel(const ushort* __restrict__ xb,
                                                   const ushort* __restrict__ yb,
                                                   const float* __restrict__ nxg,
                                                   const float* __restrict__ nyg,
                                                   ushort* __restrict__ K) {
  __shared__ ushort Ah[64 * GLDA];     // 5.1 KB
  __shared__ ushort Bh[64 * GLDA];     // 5.1 KB
  __shared__ float s_nx[64], s_ny[64];

  const int b = blockIdx.z;
  const int i0 = blockIdx.y * 64;    // m-tile (16)
  const int j0 = blockIdx.x * 64;    // n-tile (16)
  const int t = threadIdx.x;
  const int w = t >> 6, lane = t & 63;
  const int m16 = lane & 15, q = lane >> 4;
  const int wm = (w & 1) * 32, wn = (w >> 1) * 32;

  // staging: 64 rows x 32 halves each matrix (4 thr/row, 8 halves = 1 uint4)
  const int sr = t >> 2, so = (t & 3) * 8;

  const ushort* xrow = xb + ((size_t)b * NN + i0 + sr) * DD + so;
  const ushort* yrow = yb + ((size_t)b * MM + j0 + sr) * DD + so;

  f32x4 acc[2][2];
#pragma unroll
  for (int mi = 0; mi < 2; ++mi)
#pragma unroll
    for (int ni = 0; ni < 2; ++ni) acc[mi][ni] = (f32x4)0.f;

  for (int k0 = 0; k0 < DD; k0 += 32) {
    uint4 av = *(const uint4*)(xrow + k0);
    uint4 bv = *(const uint4*)(yrow + k0);
    __syncthreads();
    *(uint4*)&Ah[sr * GLDA + so] = av;
    *(uint4*)&Bh[sr * GLDA + so] = bv;
    __syncthreads();

    bf16x8 ahf[2], bhf[2];
#pragma unroll
    for (int mi = 0; mi < 2; ++mi)
      ahf[mi] = *(const bf16x8*)&Ah[(wm + mi * 16 + m16) * GLDA + q * 8];
#pragma unroll
    for (int ni = 0; ni < 2; ++ni)
      bhf[ni] = *(const bf16x8*)&Bh[(wn + ni * 16 + m16) * GLDA + q * 8];
#pragma unroll
    for (int mi = 0; mi < 2; ++mi)
#pragma unroll
      for (int ni = 0; ni < 2; ++ni)
        acc[mi][ni] = __builtin_amdgcn_mfma_f32_16x16x32_bf16(ahf[mi], bhf[ni], acc[mi][ni], 0, 0, 0);
  }

  // epilogue: K = exp(-(1 - dot/den)/eps), bf16
  if (t < 64) s_nx[t] = nxg[b * NN + i0 + t];
  else if (t < 128) s_ny[t - 64] = nyg[b * MM + j0 + t - 64];
  __syncthreads();

#pragma unroll
  for (int mi = 0; mi < 2; ++mi)
#pragma unroll
    for (int ni = 0; ni < 2; ++ni)
#pragma unroll
      for (int r = 0; r < 4; ++r) {
        const int m = wm + mi * 16 + q * 4 + r;
        const int n = wn + ni * 16 + m16;
        float den = fmaxf(s_nx[m] * s_ny[n], 1e-8f);
        float cv = 1.0f - acc[mi][ni][r] / den;
        float kf = __expf(-cv * INV_EPS);
        __bf16 hb = (__bf16)kf;
        K[((size_t)b * NN + i0 + m) * MM + j0 + n] = *(ushort*)&hb;
      }
}

__device__ __forceinline__ void unpack8(uint4 k, float* kf) {
  kf[0] = __uint_as_float(k.x << 16);
  kf[1] = __uint_as_float(k.x & 0xffff0000u);
  kf[2] = __uint_as_float(k.y << 16);
  kf[3] = __uint_as_float(k.y & 0xffff0000u);
  kf[4] = __uint_as_float(k.z << 16);
  kf[5] = __uint_as_float(k.z & 0xffff0000u);
  kf[6] = __uint_as_float(k.w << 16);
  kf[7] = __uint_as_float(k.w & 0xffff0000u);
}

// -------- persistent Sinkhorn, ONE barrier per iteration (round-1/8 proven;
// only change: dead-rotation-buffer zeroing moved to the TOP of the iteration,
// off the end-of-iteration drain critical path. Safety: that buffer's last
// readers finished before the gen-it flags this block observed on entry; the
// end-of-iteration vmcnt(0) still orders the zeros before the gen-it+1 flag,
// so iteration it+1's atomic adds never race the zeroing.) --------
__global__ void __launch_bounds__(TBLK, 2) sinkhorn_kernel(
    const ushort* __restrict__ K, float* __restrict__ colsum,
    const float* __restrict__ nup, u64* __restrict__ flags,
    float* __restrict__ out) {
  const int tid = threadIdx.x;
  const int bid = blockIdx.x;
  const int lane = tid & 63;
  const int w = tid >> 6;                 // 0..7
  const int b = bid >> 5;                 // batch (32 blocks per batch)
  const int rbase = (bid & 31) * 32;      // first owned row within batch

  __shared__ float swv[1024];
  __shared__ float spart[8][1024];        // 32 KB per-wave column partials
  __shared__ float s_red;
  __shared__ int s_conv;

  const float eps_log_mu = EPS * __logf(MU_P);
  float u_prev[4] = {0.f, 0.f, 0.f, 0.f};
  float wu_reg[4] = {0.f, 0.f, 0.f, 0.f};
  int T = 0;

  // ---- hoist this wave's 4 K-rows into registers, unpacked fp32 ----
  float kf[4][16];
#pragma unroll
  for (int rr = 0; rr < 4; ++rr) {
    const uint4* kp = (const uint4*)(K + ((size_t)b * NN + rbase + w * 4 + rr) * MM);
    uint4 k0 = kp[lane];
    uint4 k1 = kp[lane + 64];
    unpack8(k0, kf[rr]);
    unpack8(k1, kf[rr] + 8);
  }

  for (int it = 0; it < MAX_IT; ++it) {
    const int genv = it + 1;
    // ---- stage wv (local v reconstruction; it=0: v=0 -> wv=1) ----
    if (tid == 0) s_red = 0.f;
    if (it == 0) {
      swv[tid] = 1.f;
      swv[tid + 512] = 1.f;
    } else {
      const float* cs = colsum + (it % 3) * 4096 + b * MM;
      float c0 = __hip_atomic_load(cs + tid, __ATOMIC_RELAXED, __HIP_MEMORY_SCOPE_AGENT);
      float c1 = __hip_atomic_load(cs + tid + 512, __ATOMIC_RELAXED, __HIP_MEMORY_SCOPE_AGENT);
      swv[tid] = nup[b * MM + tid] / c0;
      swv[tid + 512] = nup[b * MM + tid + 512] / c1;
    }
    __syncthreads();

    // zero the dead rotation buffer EARLY (stores complete during compute;
    // still covered by the end-of-iteration vmcnt(0) drain)
    if (tid < 32) {
      float* csz = colsum + ((it + 2) % 3) * 4096;
      __hip_atomic_store(&csz[bid * 32 + tid], 0.f, __ATOMIC_RELAXED, __HIP_MEMORY_SCOPE_AGENT);
    }

    float wvr[16];
    {
      const float4* wp = (const float4*)swv;
      *(float4*)&wvr[0] = wp[lane * 2];
      *(float4*)&wvr[4] = wp[lane * 2 + 1];
      *(float4*)&wvr[8] = wp[128 + lane * 2];
      *(float4*)&wvr[12] = wp[129 + lane * 2];
    }
    float creg[16];
#pragma unroll
    for (int t2 = 0; t2 < 16; ++t2) creg[t2] = 0.f;

    float werr = 0.f;
#pragma unroll
    for (int rr = 0; rr < 4; ++rr) {
      float s = 0.f;
#pragma unroll
      for (int t2 = 0; t2 < 16; ++t2) s = fmaf(kf[rr][t2], wvr[t2], s);
      s = wave_reduce_sum(s);
      float unv = eps_log_mu - EPS * __logf(s);
      werr += fabsf(unv - u_prev[rr]);
      u_prev[rr] = unv;
      float wu = MU_P / s;          // exp(u_new/eps), exactly
      wu_reg[rr] = wu;
#pragma unroll
      for (int t2 = 0; t2 < 16; ++t2) creg[t2] = fmaf(wu, kf[rr][t2], creg[t2]);
    }
    if (lane == 0) atomicAdd(&s_red, werr);

    // publish per-wave column partials to LDS
    {
      float* pr = &spart[w][0];
      *(float4*)&pr[lane * 8] = *(float4*)&creg[0];
      *(float4*)&pr[lane * 8 + 4] = *(float4*)&creg[4];
      *(float4*)&pr[512 + lane * 8] = *(float4*)&creg[8];
      *(float4*)&pr[512 + lane * 8 + 4] = *(float4*)&creg[12];
    }
    __syncthreads();

    // cross-wave reduce + atomic add into next colsum
    {
      float* csn = colsum + ((it + 1) % 3) * 4096 + b * MM;
      const int j0 = tid * 2;
      float s0 = 0.f, s1 = 0.f;
#pragma unroll
      for (int ww = 0; ww < 8; ++ww) {
        float2 p = *(const float2*)&spart[ww][j0];
        s0 += p.x;
        s1 += p.y;
      }
      unsafeAtomicAdd(&csn[j0], s0);
      unsafeAtomicAdd(&csn[j0 + 1], s1);
    }

    // ---- all-to-all barrier: publish {gen, err}, poll, local conv decision ----
    asm volatile("s_waitcnt vmcnt(0)" ::: "memory");
    __syncthreads();
    if (tid == 0) {
      u64 f = ((u64)(uint)genv << 32) | (u64)__float_as_uint(s_red);
      __hip_atomic_store(&flags[(genv & 1) * GBLK + bid], f, __ATOMIC_RELAXED, __HIP_MEMORY_SCOPE_AGENT);
    }
    if (tid < 64) {
      const u64* fl = flags + (genv & 1) * GBLK;
      u64 f0, f1;
      for (;;) {
        f0 = __hip_atomic_load(fl + tid, __ATOMIC_RELAXED, __HIP_MEMORY_SCOPE_AGENT);
        f1 = __hip_atomic_load(fl + tid + 64, __ATOMIC_RELAXED, __HIP_MEMORY_SCOPE_AGENT);
        if (__all(((f0 >> 32) >= (u64)genv) && ((f1 >> 32) >= (u64)genv))) break;
        __builtin_amdgcn_s_sleep(1);
      }
      float e = __uint_as_float((uint)f0) + __uint_as_float((uint)f1);
      e = wave_reduce_sum(e);
      if (tid == 0) s_conv = (e * (1.0f / (float)BB) < THRESH) ? 1 : 0;
    }
    __syncthreads();
    T = it;
    if (s_conv) break;
  }

  // ---- final: reconstruct converged wv locally, accumulate transport cost ----
  {
    const float* cs = colsum + ((T + 1) % 3) * 4096 + b * MM;
    float c0 = __hip_atomic_load(cs + tid, __ATOMIC_RELAXED, __HIP_MEMORY_SCOPE_AGENT);
    float c1 = __hip_atomic_load(cs + tid + 512, __ATOMIC_RELAXED, __HIP_MEMORY_SCOPE_AGENT);
    swv[tid] = nup[b * MM + tid] / c0;
    swv[tid + 512] = nup[b * MM + tid + 512] / c1;
  }
  if (tid == 0) s_red = 0.f;
  __syncthreads();

  float wvr[16];
  {
    const float4* wp = (const float4*)swv;
    *(float4*)&wvr[0] = wp[lane * 2];
    *(float4*)&wvr[4] = wp[lane * 2 + 1];
    *(float4*)&wvr[8] = wp[128 + lane * 2];
    *(float4*)&wvr[12] = wp[129 + lane * 2];
  }

  float wcost = 0.f;
#pragma unroll
  for (int rr = 0; rr < 4; ++rr) {
    float s = 0.f;
#pragma unroll
    for (int t2 = 0; t2 < 16; ++t2)
      s = fmaf(kf[rr][t2] * wvr[t2], -EPS * __logf(kf[rr][t2]), s);   // pi * C, C = -eps log K
    s = wave_reduce_sum(s) * wu_reg[rr];
    if (lane == 0) wcost += s;
  }
  if (lane == 0) atomicAdd(&s_red, wcost);
  __syncthreads();
  if (tid == 0) atomicAdd(out + b, s_red);
}

extern "C" void kernel_launch(void* const* d_in, const int* in_sizes, int n_in,
                              void* d_out, int out_size, void* d_ws, size_t ws_size,
                              hipStream_t stream) {
  const float* x = (const float*)d_in[0];
  const float* y = (const float*)d_in[1];
  const float* nu = (const float*)d_in[2];
  float* out = (float*)d_out;
  float* ws = (float*)d_ws;

  ushort* K = (ushort*)(ws + OFF_K);
  ushort* xb = (ushort*)(ws + OFF_XB);
  ushort* yb = (ushort*)(ws + OFF_YB);
  float* nx = ws + OFF_NX;
  float* ny = ws + OFF_NY;
  float* nup = ws + OFF_NUP;
  float* cs = ws + OFF_CS;
  u64* flg = (u64*)(ws + OFF_FLG);

  prep_kernel<<<2048, 256, 0, stream>>>(x, y, xb, yb, nx, ny, nu, nup, cs, (int*)flg, out);
  gemm_kernel<<<dim3(16, 16, 4), 256, 0, stream>>>(xb, yb, nx, ny, K);

  sinkhorn_kernel<<<GBLK, TBLK, 0, stream>>>(K, cs, nup, flg, out);
}